// Round 1
// baseline (155.692 us; speedup 1.0000x reference)
//
#include <hip/hip_runtime.h>
#include <hip/hip_bf16.h>
#include <math.h>

// Sizes (fixed by the reference):
//   B=256, VIS=1024, BOT=64, CTX=512, H=16, MLP_H=4
// Inputs (d_in order):
//   0: x        (256,1024) f32
//   1: reduce_w (1024,64)  f32
//   2: reduce_b (64,)      f32
//   3: ann_w1   (64,4)     f32
//   4: ann_b1   (4,)       f32
//   5: ann_w2   (4,512)    f32
//   6: ann_b2   (512,)     f32
//   7: kan_W1   (64,512,16) f32
//   8: kan_b1   (64,512,16) f32
//   9: kan_W2   (64,512,16) f32
//  10: kan_b2   (64,512)   f32
//  11: gate_w   (64,512)   f32
//  12: gate_b   (512,)     f32
// Output: (256,512) f32

#define B_SZ   256
#define VIS    1024
#define BOT    64
#define CTX    512
#define KH     16
#define MLP_H  4

// Kernel 1: z = x @ reduce_w + reduce_b  (written TRANSPOSED: zT[i*256 + b])
//           a4 = relu(z @ ann_w1 + ann_b1)  (a4[b*4 + m])
// One block per batch row b; 256 threads.
__global__ __launch_bounds__(256) void k1_reduce(
    const float* __restrict__ x,
    const float* __restrict__ rw,
    const float* __restrict__ rb,
    const float* __restrict__ aw1,
    const float* __restrict__ ab1,
    float* __restrict__ zT,
    float* __restrict__ a4)
{
    __shared__ float xs[VIS];
    __shared__ float zp[4][BOT];
    __shared__ float zs[BOT];

    const int b = blockIdx.x;
    const int t = threadIdx.x;

    // Stage x row: 256 threads x float4 = 4 KB, fully coalesced.
    ((float4*)xs)[t] = ((const float4*)(x + (size_t)b * VIS))[t];
    __syncthreads();

    // Thread t: output j = t&63, k-chunk c = t>>6 (4 chunks of 256 terms).
    const int j = t & 63;
    const int c = t >> 6;
    const float* wp = rw + (size_t)c * 256 * BOT + j;  // rw[k][j], k = c*256 + kk
    const float* xp = xs + c * 256;
    float p = 0.f;
#pragma unroll 8
    for (int kk = 0; kk < 256; ++kk) {
        p = fmaf(xp[kk], wp[(size_t)kk * BOT], p);
    }
    zp[c][j] = p;
    __syncthreads();

    if (t < BOT) {
        float z = zp[0][t] + zp[1][t] + zp[2][t] + zp[3][t] + rb[t];
        zs[t] = z;
        zT[(size_t)t * B_SZ + b] = z;   // transposed: i-major
    }
    __syncthreads();

    if (t < MLP_H) {
        float s = ab1[t];
#pragma unroll 8
        for (int i = 0; i < BOT; ++i) s = fmaf(zs[i], aw1[i * MLP_H + t], s);
        a4[b * MLP_H + t] = fmaxf(s, 0.f);
    }
}

// Kernel 2: per block = one output column o; per thread = one batch b.
// All weight accesses are block-uniform -> scalar (s_load) broadcast.
// Per-lane traffic: 64 coalesced z loads + 1 float4 a4 load + 1 store.
__global__ __launch_bounds__(256) void k2_main(
    const float* __restrict__ zT,
    const float* __restrict__ a4,
    const float* __restrict__ aw2,
    const float* __restrict__ ab2,
    const float* __restrict__ kW1,
    const float* __restrict__ kb1,
    const float* __restrict__ kW2,
    const float* __restrict__ kb2,
    const float* __restrict__ gw,
    const float* __restrict__ gb,
    float* __restrict__ out)
{
    const int o = blockIdx.x;
    const int b = threadIdx.x;

    float accK = 0.f;
    float accG = 0.f;

#pragma unroll 2
    for (int i = 0; i < BOT; ++i) {
        const float z = zT[(size_t)i * B_SZ + b];          // coalesced, L2-resident
        const float* __restrict__ w1 = kW1 + ((size_t)(i * CTX + o)) * KH;  // uniform
        const float* __restrict__ b1 = kb1 + ((size_t)(i * CTX + o)) * KH;
        const float* __restrict__ w2 = kW2 + ((size_t)(i * CTX + o)) * KH;
#pragma unroll
        for (int h = 0; h < KH; ++h) {
            float hv = fmaf(z, w1[h], b1[h]);
            hv = fmaxf(hv, 0.f);
            accK = fmaf(hv, w2[h], accK);
        }
        accG = fmaf(z + 1.f, gw[i * CTX + o], accG);        // gate dot, uniform weight
    }

    // kan_b2.sum(axis=0)[o] — uniform across the block; cheap scalar loop.
    float kb2s = 0.f;
#pragma unroll 8
    for (int i = 0; i < BOT; ++i) kb2s += kb2[i * CTX + o];

    // ANN epilogue: a4[b,:4] (vector) dot ann_w2[:,o] (uniform) + ann_b2[o].
    const float4 av = *(const float4*)(a4 + b * MLP_H);
    float ann = ab2[o];
    ann = fmaf(av.x, aw2[0 * CTX + o], ann);
    ann = fmaf(av.y, aw2[1 * CTX + o], ann);
    ann = fmaf(av.z, aw2[2 * CTX + o], ann);
    ann = fmaf(av.w, aw2[3 * CTX + o], ann);

    // Gate
    const float g = 1.f / (1.f + __expf(-(accG + gb[o])));

    out[(size_t)b * CTX + o] = g * ann + (1.f - g) * (accK + kb2s);
}

extern "C" void kernel_launch(void* const* d_in, const int* in_sizes, int n_in,
                              void* d_out, int out_size, void* d_ws, size_t ws_size,
                              hipStream_t stream)
{
    const float* x   = (const float*)d_in[0];
    const float* rw  = (const float*)d_in[1];
    const float* rb  = (const float*)d_in[2];
    const float* aw1 = (const float*)d_in[3];
    const float* ab1 = (const float*)d_in[4];
    const float* aw2 = (const float*)d_in[5];
    const float* ab2 = (const float*)d_in[6];
    const float* kW1 = (const float*)d_in[7];
    const float* kb1 = (const float*)d_in[8];
    const float* kW2 = (const float*)d_in[9];
    const float* kb2 = (const float*)d_in[10];
    const float* gw  = (const float*)d_in[11];
    const float* gb  = (const float*)d_in[12];
    float* out = (float*)d_out;

    // Workspace layout: zT (64*256 f32 = 64 KB) | a4 (256*4 f32 = 4 KB)
    float* zT = (float*)d_ws;
    float* a4 = zT + (size_t)BOT * B_SZ;

    k1_reduce<<<B_SZ, 256, 0, stream>>>(x, rw, rb, aw1, ab1, zT, a4);
    k2_main<<<CTX, 256, 0, stream>>>(zT, a4, aw2, ab2, kW1, kb1, kW2, kb2, gw, gb, out);
}

// Round 2
// 114.718 us; speedup vs baseline: 1.3572x; 1.3572x over previous
//
#include <hip/hip_runtime.h>
#include <hip/hip_bf16.h>
#include <math.h>

// Sizes (fixed): B=256, VIS=1024, BOT=64, CTX=512, H=16, MLP_H=4
#define B_SZ   256
#define VIS    1024
#define BOT    64
#define CTX    512
#define KH     16
#define MLP_H  4

// ---------------------------------------------------------------------------
// k0: column pre-sums over i:  kb2s[o] = sum_i kan_b2[i,o],  gwsum[o] = sum_i gate_w[i,o]
// (folds the "+1" of the gate:  (z+1)@gw = z@gw + gwsum)
// ---------------------------------------------------------------------------
__global__ __launch_bounds__(256) void k0_presum(
    const float* __restrict__ kb2,
    const float* __restrict__ gw,
    float* __restrict__ kb2s,
    float* __restrict__ gwsum)
{
    const int o = blockIdx.x * 256 + threadIdx.x;   // grid 2 x 256 = 512
    float s0 = 0.f, s1 = 0.f;
#pragma unroll 8
    for (int i = 0; i < BOT; ++i) {
        s0 += kb2[i * CTX + o];   // coalesced across o lanes
        s1 += gw[i * CTX + o];
    }
    kb2s[o]  = s0;
    gwsum[o] = s1;
}

// ---------------------------------------------------------------------------
// k1: z = x @ reduce_w + reduce_b, written transposed zT[i*256+b];
//     a4 = relu(z @ ann_w1 + ann_b1).
// One block per batch row. Lanes over j (coalesced rw rows), waves over k-chunks.
// x[b,k] is wave-uniform -> scalar loads.
// ---------------------------------------------------------------------------
__global__ __launch_bounds__(256) void k1_reduce(
    const float* __restrict__ x,
    const float* __restrict__ rw,
    const float* __restrict__ rb,
    const float* __restrict__ aw1,
    const float* __restrict__ ab1,
    float* __restrict__ zT,
    float* __restrict__ a4)
{
    __shared__ float zp[4][BOT];
    __shared__ float zs[BOT];

    const int b = blockIdx.x;
    const int t = threadIdx.x;
    const int w = t >> 6;        // k-chunk 0..3 (256 k each)
    const int j = t & 63;        // output column 0..63

    const float* __restrict__ xr = x + (size_t)b * VIS + w * 256;   // uniform per wave
    const float* __restrict__ wr = rw + (size_t)w * 256 * BOT;

    float p = 0.f;
#pragma unroll 8
    for (int k = 0; k < 256; ++k)
        p = fmaf(xr[k], wr[(size_t)k * BOT + j], p);   // xr[k] scalar; wr coalesced 256B/row

    zp[w][j] = p;
    __syncthreads();

    if (t < BOT) {
        float z = zp[0][t] + zp[1][t] + zp[2][t] + zp[3][t] + rb[t];
        zs[t] = z;
        zT[(size_t)t * B_SZ + b] = z;   // transposed: i-major (k2 reads rows of 16 b)
    }
    __syncthreads();

    if (t < MLP_H) {
        float s = ab1[t];
#pragma unroll
        for (int i = 0; i < BOT; ++i) s = fmaf(zs[i], aw1[i * MLP_H + t], s);
        a4[b * MLP_H + t] = fmaxf(s, 0.f);
    }
}

// ---------------------------------------------------------------------------
// k2: KAN + gate + epilogue.
// Block = 256 threads = 4 waves. Block tile: 16 o x 16 b; wave = one i-chunk of 16.
// Lane l: o_l = l>>2 (16 o), hq = l&3 (h-quad). Weight loads are float4,
// lane-contiguous (1KB/wave/array per i). z is block-uniform -> s_load.
// Each lane keeps a 16-b accumulator tile in regs (16 independent FMA chains).
// ---------------------------------------------------------------------------
__global__ __launch_bounds__(256) void k2_main(
    const float* __restrict__ zT,
    const float* __restrict__ a4,
    const float* __restrict__ aw2,
    const float* __restrict__ ab2,
    const float* __restrict__ kW1,
    const float* __restrict__ kb1,
    const float* __restrict__ kW2,
    const float* __restrict__ gw,
    const float* __restrict__ gb,
    const float* __restrict__ kb2s,
    const float* __restrict__ gwsum,
    float* __restrict__ out)
{
    // pad inner dim to 20 floats (80B): keeps float4 stores 16B-aligned, spreads banks
    __shared__ float pK[4][4][16][20];   // [wave][hq][o][b]
    __shared__ float pG[4][16][20];      // [wave][o][b]

    const int t    = threadIdx.x;
    const int w    = t >> 6;
    const int lane = t & 63;
    const int o_l  = lane >> 2;
    const int hq   = lane & 3;
    const int o0   = blockIdx.x * 16;
    const int b0   = blockIdx.y * 16;

    float4 acc[16];
    float  accG[16];
#pragma unroll
    for (int b = 0; b < 16; ++b) {
        acc[b] = make_float4(0.f, 0.f, 0.f, 0.f);
        accG[b] = 0.f;
    }

    const int i0 = w * 16;
#pragma unroll 2
    for (int ii = 0; ii < 16; ++ii) {
        const int i = i0 + ii;
        const size_t wb = ((size_t)i * CTX + o0) * KH + (size_t)lane * 4;
        const float4 w1 = *(const float4*)(kW1 + wb);
        const float4 b1 = *(const float4*)(kb1 + wb);
        const float4 w2 = *(const float4*)(kW2 + wb);
        const float  gwv = gw[i * CTX + o0 + o_l];
        const float* __restrict__ zp = zT + (size_t)i * B_SZ + b0;  // uniform -> s_load x16
#pragma unroll
        for (int b = 0; b < 16; ++b) {
            const float z = zp[b];
            float4 hv;
            hv.x = fmaxf(fmaf(z, w1.x, b1.x), 0.f);
            hv.y = fmaxf(fmaf(z, w1.y, b1.y), 0.f);
            hv.z = fmaxf(fmaf(z, w1.z, b1.z), 0.f);
            hv.w = fmaxf(fmaf(z, w1.w, b1.w), 0.f);
            acc[b].x = fmaf(hv.x, w2.x, acc[b].x);
            acc[b].y = fmaf(hv.y, w2.y, acc[b].y);
            acc[b].z = fmaf(hv.z, w2.z, acc[b].z);
            acc[b].w = fmaf(hv.w, w2.w, acc[b].w);
            accG[b]  = fmaf(z, gwv, accG[b]);
        }
    }

    // in-lane h-quad sums (per-b), all indices compile-time
    float aK[16];
#pragma unroll
    for (int b = 0; b < 16; ++b)
        aK[b] = (acc[b].x + acc[b].y) + (acc[b].z + acc[b].w);

    // every lane dumps its 16-b partial row into its own [w][hq][o_l] slot
    {
        float* d = &pK[w][hq][o_l][0];
        ((float4*)d)[0] = make_float4(aK[0],  aK[1],  aK[2],  aK[3]);
        ((float4*)d)[1] = make_float4(aK[4],  aK[5],  aK[6],  aK[7]);
        ((float4*)d)[2] = make_float4(aK[8],  aK[9],  aK[10], aK[11]);
        ((float4*)d)[3] = make_float4(aK[12], aK[13], aK[14], aK[15]);
    }
    if (hq == 0) {   // gate partials identical across hq lanes; one writer
        float* d = &pG[w][o_l][0];
        ((float4*)d)[0] = make_float4(accG[0],  accG[1],  accG[2],  accG[3]);
        ((float4*)d)[1] = make_float4(accG[4],  accG[5],  accG[6],  accG[7]);
        ((float4*)d)[2] = make_float4(accG[8],  accG[9],  accG[10], accG[11]);
        ((float4*)d)[3] = make_float4(accG[12], accG[13], accG[14], accG[15]);
    }
    __syncthreads();

    // combine + epilogue: thread -> (o = t&15, b = t>>4); stores are 64B-chunked
    {
        const int o = t & 15;
        const int b = t >> 4;
        float sK = 0.f, sG = 0.f;
#pragma unroll
        for (int w2 = 0; w2 < 4; ++w2) {
#pragma unroll
            for (int h2 = 0; h2 < 4; ++h2)
                sK += pK[w2][h2][o][b];
            sG += pG[w2][o][b];
        }
        const int oo = o0 + o;
        const int bb = b0 + b;
        sK += kb2s[oo];
        sG += gwsum[oo] + gb[oo];

        const float4 av = *(const float4*)(a4 + bb * MLP_H);
        float ann = ab2[oo];
        ann = fmaf(av.x, aw2[0 * CTX + oo], ann);
        ann = fmaf(av.y, aw2[1 * CTX + oo], ann);
        ann = fmaf(av.z, aw2[2 * CTX + oo], ann);
        ann = fmaf(av.w, aw2[3 * CTX + oo], ann);

        const float g = 1.f / (1.f + __expf(-sG));
        out[(size_t)bb * CTX + oo] = g * ann + (1.f - g) * sK;
    }
}

extern "C" void kernel_launch(void* const* d_in, const int* in_sizes, int n_in,
                              void* d_out, int out_size, void* d_ws, size_t ws_size,
                              hipStream_t stream)
{
    const float* x   = (const float*)d_in[0];
    const float* rw  = (const float*)d_in[1];
    const float* rb  = (const float*)d_in[2];
    const float* aw1 = (const float*)d_in[3];
    const float* ab1 = (const float*)d_in[4];
    const float* aw2 = (const float*)d_in[5];
    const float* ab2 = (const float*)d_in[6];
    const float* kW1 = (const float*)d_in[7];
    const float* kb1 = (const float*)d_in[8];
    const float* kW2 = (const float*)d_in[9];
    const float* kb2 = (const float*)d_in[10];
    const float* gw  = (const float*)d_in[11];
    const float* gb  = (const float*)d_in[12];
    float* out = (float*)d_out;

    // ws layout: zT (64*256) | a4 (256*4) | kb2s (512) | gwsum (512)  = ~72KB
    float* zT    = (float*)d_ws;
    float* a4    = zT + (size_t)BOT * B_SZ;
    float* kb2s  = a4 + (size_t)B_SZ * MLP_H;
    float* gwsum = kb2s + CTX;

    k0_presum<<<2, 256, 0, stream>>>(kb2, gw, kb2s, gwsum);
    k1_reduce<<<B_SZ, 256, 0, stream>>>(x, rw, rb, aw1, ab1, zT, a4);
    k2_main<<<dim3(CTX / 16, B_SZ / 16), 256, 0, stream>>>(
        zT, a4, aw2, ab2, kW1, kb1, kW2, gw, gb, kb2s, gwsum, out);
}

// Round 3
// 100.980 us; speedup vs baseline: 1.5418x; 1.1361x over previous
//
#include <hip/hip_runtime.h>
#include <hip/hip_bf16.h>
#include <math.h>

// Sizes (fixed): B=256, VIS=1024, BOT=64, CTX=512, H=16, MLP_H=4
#define B_SZ   256
#define VIS    1024
#define BOT    64
#define CTX    512
#define KH     16
#define MLP_H  4

// ---------------------------------------------------------------------------
// kA: fused. Blocks 0..255: z-row for batch b (+ a4). Blocks 256..263: column
// pre-sums kb2s[o]=sum_i kan_b2[i,o], gwsum[o]=sum_i gate_w[i,o] (gate "+1" fold).
// z-part: wave w = k-chunk of 256; lane l: kq=l>>4 (k-subchunk of 64),
// jq=l&15 (j-quad, float4 rw loads). 4 independent FMA chains/thread,
// 64 load-batches instead of 256 -> deep vmcnt pipelining.
// ---------------------------------------------------------------------------
__global__ __launch_bounds__(256) void kA(
    const float* __restrict__ x,
    const float* __restrict__ rw,
    const float* __restrict__ rb,
    const float* __restrict__ aw1,
    const float* __restrict__ ab1,
    const float* __restrict__ kb2,
    const float* __restrict__ gw,
    float* __restrict__ zT,
    float* __restrict__ a4,
    float* __restrict__ kb2s,
    float* __restrict__ gwsum)
{
    const int t = threadIdx.x;

    if (blockIdx.x >= B_SZ) {
        // ---- presum part: 8 blocks x 64 o; waves over i-chunks of 16 ----
        __shared__ float r0[4][64], r1[4][64];
        const int blk = blockIdx.x - B_SZ;
        const int w = t >> 6, l = t & 63;
        const int o = blk * 64 + l;
        float s0 = 0.f, s1 = 0.f;
#pragma unroll
        for (int ii = 0; ii < 16; ++ii) {
            const int i = w * 16 + ii;
            s0 += kb2[i * CTX + o];     // coalesced 256B/wave
            s1 += gw[i * CTX + o];
        }
        r0[w][l] = s0; r1[w][l] = s1;
        __syncthreads();
        if (t < 64) {
            kb2s[blk * 64 + t]  = r0[0][t] + r0[1][t] + r0[2][t] + r0[3][t];
            gwsum[blk * 64 + t] = r1[0][t] + r1[1][t] + r1[2][t] + r1[3][t];
        }
        return;
    }

    // ---- z part ----
    const int b  = blockIdx.x;
    const int w  = t >> 6, l = t & 63;
    const int kq = l >> 4, jq = l & 15;
    const int kbase = w * 256 + kq * 64;

    const float*  __restrict__ xb = x + (size_t)b * VIS + kbase;
    const float4* __restrict__ wb = (const float4*)rw + (size_t)kbase * 16 + jq;

    float4 a = make_float4(0.f, 0.f, 0.f, 0.f);
#pragma unroll 8
    for (int tt = 0; tt < 64; ++tt) {
        const float  xv = xb[tt];                 // 4 bcast addrs/wave, L1-hot
        const float4 wv = wb[(size_t)tt * 16];    // 16B/lane, 1KB/wave coalesced
        a.x = fmaf(xv, wv.x, a.x);
        a.y = fmaf(xv, wv.y, a.y);
        a.z = fmaf(xv, wv.z, a.z);
        a.w = fmaf(xv, wv.w, a.w);
    }
    // reduce over the 4 k-subchunks (lanes xor 16, 32)
    a.x += __shfl_xor(a.x, 16, 64); a.y += __shfl_xor(a.y, 16, 64);
    a.z += __shfl_xor(a.z, 16, 64); a.w += __shfl_xor(a.w, 16, 64);
    a.x += __shfl_xor(a.x, 32, 64); a.y += __shfl_xor(a.y, 32, 64);
    a.z += __shfl_xor(a.z, 32, 64); a.w += __shfl_xor(a.w, 32, 64);

    __shared__ float4 zp[4][16];     // [wave][jq] -> j = jq*4..jq*4+3
    __shared__ float  zs[64];
    if (l < 16) zp[w][jq] = a;
    __syncthreads();

    if (t < BOT) {
        const float* z0 = (const float*)&zp[0][0];   // [w*64 + j]
        const float z = z0[t] + z0[64 + t] + z0[128 + t] + z0[192 + t] + rb[t];
        zs[t] = z;
        zT[(size_t)t * B_SZ + b] = z;   // transposed: i-major
    }
    __syncthreads();

    if (t < MLP_H) {
        float s = ab1[t];
#pragma unroll
        for (int i = 0; i < BOT; ++i) s = fmaf(zs[i], aw1[i * MLP_H + t], s);
        a4[b * MLP_H + t] = fmaxf(s, 0.f);
    }
}

// ---------------------------------------------------------------------------
// k2: KAN + gate + epilogue. Block = 4 waves, tile 16 o x 16 b; wave = i-chunk
// of 16. Lane: o_l=l>>2, hq=l&3; weights are lane-contiguous float4 loads;
// z is block-uniform (s_load). 16 independent FMA chains per lane.
// ---------------------------------------------------------------------------
__global__ __launch_bounds__(256) void k2_main(
    const float* __restrict__ zT,
    const float* __restrict__ a4,
    const float* __restrict__ aw2,
    const float* __restrict__ ab2,
    const float* __restrict__ kW1,
    const float* __restrict__ kb1,
    const float* __restrict__ kW2,
    const float* __restrict__ gw,
    const float* __restrict__ gb,
    const float* __restrict__ kb2s,
    const float* __restrict__ gwsum,
    float* __restrict__ out)
{
    __shared__ float pK[4][4][16][20];   // [wave][hq][o][b], padded
    __shared__ float pG[4][16][20];      // [wave][o][b]

    const int t    = threadIdx.x;
    const int w    = t >> 6;
    const int lane = t & 63;
    const int o_l  = lane >> 2;
    const int hq   = lane & 3;
    const int o0   = blockIdx.x * 16;
    const int b0   = blockIdx.y * 16;

    float4 acc[16];
    float  accG[16];
#pragma unroll
    for (int b = 0; b < 16; ++b) {
        acc[b] = make_float4(0.f, 0.f, 0.f, 0.f);
        accG[b] = 0.f;
    }

    const int i0 = w * 16;
#pragma unroll 2
    for (int ii = 0; ii < 16; ++ii) {
        const int i = i0 + ii;
        const size_t wbo = ((size_t)i * CTX + o0) * KH + (size_t)lane * 4;
        const float4 w1 = *(const float4*)(kW1 + wbo);
        const float4 b1 = *(const float4*)(kb1 + wbo);
        const float4 w2 = *(const float4*)(kW2 + wbo);
        const float  gwv = gw[i * CTX + o0 + o_l];
        const float* __restrict__ zp = zT + (size_t)i * B_SZ + b0;  // uniform
#pragma unroll
        for (int b = 0; b < 16; ++b) {
            const float z = zp[b];
            float4 hv;
            hv.x = fmaxf(fmaf(z, w1.x, b1.x), 0.f);
            hv.y = fmaxf(fmaf(z, w1.y, b1.y), 0.f);
            hv.z = fmaxf(fmaf(z, w1.z, b1.z), 0.f);
            hv.w = fmaxf(fmaf(z, w1.w, b1.w), 0.f);
            acc[b].x = fmaf(hv.x, w2.x, acc[b].x);
            acc[b].y = fmaf(hv.y, w2.y, acc[b].y);
            acc[b].z = fmaf(hv.z, w2.z, acc[b].z);
            acc[b].w = fmaf(hv.w, w2.w, acc[b].w);
            accG[b]  = fmaf(z, gwv, accG[b]);
        }
    }

    float aK[16];
#pragma unroll
    for (int b = 0; b < 16; ++b)
        aK[b] = (acc[b].x + acc[b].y) + (acc[b].z + acc[b].w);

    {
        float* d = &pK[w][hq][o_l][0];
        ((float4*)d)[0] = make_float4(aK[0],  aK[1],  aK[2],  aK[3]);
        ((float4*)d)[1] = make_float4(aK[4],  aK[5],  aK[6],  aK[7]);
        ((float4*)d)[2] = make_float4(aK[8],  aK[9],  aK[10], aK[11]);
        ((float4*)d)[3] = make_float4(aK[12], aK[13], aK[14], aK[15]);
    }
    if (hq == 0) {
        float* d = &pG[w][o_l][0];
        ((float4*)d)[0] = make_float4(accG[0],  accG[1],  accG[2],  accG[3]);
        ((float4*)d)[1] = make_float4(accG[4],  accG[5],  accG[6],  accG[7]);
        ((float4*)d)[2] = make_float4(accG[8],  accG[9],  accG[10], accG[11]);
        ((float4*)d)[3] = make_float4(accG[12], accG[13], accG[14], accG[15]);
    }
    __syncthreads();

    {
        const int o = t & 15;
        const int b = t >> 4;
        float sK = 0.f, sG = 0.f;
#pragma unroll
        for (int w2 = 0; w2 < 4; ++w2) {
#pragma unroll
            for (int h2 = 0; h2 < 4; ++h2)
                sK += pK[w2][h2][o][b];
            sG += pG[w2][o][b];
        }
        const int oo = o0 + o;
        const int bb = b0 + b;
        sK += kb2s[oo];
        sG += gwsum[oo] + gb[oo];

        const float4 av = *(const float4*)(a4 + bb * MLP_H);
        float ann = ab2[oo];
        ann = fmaf(av.x, aw2[0 * CTX + oo], ann);
        ann = fmaf(av.y, aw2[1 * CTX + oo], ann);
        ann = fmaf(av.z, aw2[2 * CTX + oo], ann);
        ann = fmaf(av.w, aw2[3 * CTX + oo], ann);

        const float g = 1.f / (1.f + __expf(-sG));
        out[(size_t)bb * CTX + oo] = g * ann + (1.f - g) * sK;
    }
}

extern "C" void kernel_launch(void* const* d_in, const int* in_sizes, int n_in,
                              void* d_out, int out_size, void* d_ws, size_t ws_size,
                              hipStream_t stream)
{
    const float* x   = (const float*)d_in[0];
    const float* rw  = (const float*)d_in[1];
    const float* rb  = (const float*)d_in[2];
    const float* aw1 = (const float*)d_in[3];
    const float* ab1 = (const float*)d_in[4];
    const float* aw2 = (const float*)d_in[5];
    const float* ab2 = (const float*)d_in[6];
    const float* kW1 = (const float*)d_in[7];
    const float* kb1 = (const float*)d_in[8];
    const float* kW2 = (const float*)d_in[9];
    const float* kb2 = (const float*)d_in[10];
    const float* gw  = (const float*)d_in[11];
    const float* gb  = (const float*)d_in[12];
    float* out = (float*)d_out;

    // ws layout: zT (64*256) | a4 (256*4) | kb2s (512) | gwsum (512)
    float* zT    = (float*)d_ws;
    float* a4    = zT + (size_t)BOT * B_SZ;
    float* kb2s  = a4 + (size_t)B_SZ * MLP_H;
    float* gwsum = kb2s + CTX;

    kA<<<B_SZ + 8, 256, 0, stream>>>(x, rw, rb, aw1, ab1, kb2, gw,
                                     zT, a4, kb2s, gwsum);
    k2_main<<<dim3(CTX / 16, B_SZ / 16), 256, 0, stream>>>(
        zT, a4, aw2, ab2, kW1, kb1, kW2, gw, gb, kb2s, gwsum, out);
}